// Round 2
// baseline (10953.030 us; speedup 1.0000x reference)
//
#include <hip/hip_runtime.h>
#include <hip/hip_bf16.h>

#define T_SEQ 256
#define BATCH 256
#define HID   1024
#define EMB   10
#define VOCABN 10
#define NCLS  10

typedef __attribute__((ext_vector_type(8))) short short8;
typedef __attribute__((ext_vector_type(4))) float floatx4;

// ---- workspace layout (bytes) ----
#define OFF_WHB   0                                // 4096*1024 bf16 = 8 MB
#define OFF_PTAB  (8*1024*1024)                    // 10*4096 f32 = 160 KB
#define OFF_H0    (OFF_PTAB + 160*1024)            // 256*1024 bf16 = 512 KB
#define OFF_H1    (OFF_H0 + BATCH*HID*2)
#define OFF_BAR   (OFF_H1 + BATCH*HID*2)           // 256 uints (4 counters @ stride 64)

__device__ __forceinline__ float fsig(float x) {
    return __builtin_amdgcn_rcpf(1.0f + __expf(-x));
}
__device__ __forceinline__ float ftanh(float x) {
    return 2.0f * fsig(2.0f * x) - 1.0f;
}

// One-shot prep: cast Wh -> bf16 gate-major; build ptab; zero h0 + barrier counters.
__global__ __launch_bounds__(256)
void prep_kernel(const float* __restrict__ Wgh, const float* __restrict__ Wih,
                 const float* __restrict__ Wfh, const float* __restrict__ Woh,
                 const float* __restrict__ embed,
                 const float* __restrict__ Wgx, const float* __restrict__ Wix,
                 const float* __restrict__ Wfx, const float* __restrict__ Wox,
                 const float* __restrict__ bg, const float* __restrict__ bi,
                 const float* __restrict__ bf, const float* __restrict__ bo,
                 __hip_bfloat16* __restrict__ whb, float* __restrict__ ptab,
                 __hip_bfloat16* __restrict__ h0, unsigned* __restrict__ bar)
{
    int idx = blockIdx.x * 256 + threadIdx.x;   // 0 .. 4194303
    {
        int gate = idx >> 20;
        int rem  = idx & 0xFFFFF;
        const float* W = (gate == 0) ? Wgh : (gate == 1) ? Wih : (gate == 2) ? Wfh : Woh;
        whb[idx] = __float2bfloat16(W[rem]);
    }
    if (idx < VOCABN * 4 * HID) {               // ptab[v*4096 + g]
        int v = idx >> 12;
        int g = idx & 4095;
        int gg = g >> 10;
        int j  = g & 1023;
        const float* Wx = (gg == 0) ? Wgx : (gg == 1) ? Wix : (gg == 2) ? Wfx : Wox;
        const float* bb = (gg == 0) ? bg  : (gg == 1) ? bi  : (gg == 2) ? bf  : bo;
        float s = bb[j];
        #pragma unroll
        for (int e = 0; e < EMB; ++e) s += embed[v * EMB + e] * Wx[j * EMB + e];
        ptab[idx] = s;
    }
    if (idx < BATCH * HID) h0[idx] = __float2bfloat16(0.0f);
    if (idx < 256) bar[idx] = 0u;
}

// Persistent LSTM: weights stationary in registers across all 256 timesteps.
// Grid 256 WGs x 256 threads (1 WG/CU forced by 82.5KB LDS).
// WG (bt = blk&3, ht = blk>>2): batch-tile 64, hidden-tile 16 (x4 gates).
// Wave w: K-slice [256w, 256w+256); B-frags (16 hid x 4 gates x 256 K) in 128 VGPRs.
// Post-reduction wave w owns M-tile w (16 batches x 16 hidden); c lives in registers.
__global__ __launch_bounds__(256, 1)
void lstm_persist(const int* __restrict__ x, const float* __restrict__ ptab,
                  const __hip_bfloat16* __restrict__ whb,
                  __hip_bfloat16* __restrict__ h0buf,
                  __hip_bfloat16* __restrict__ h1buf,
                  unsigned* __restrict__ bar)
{
    __shared__ float red[4 * 4 * 4 * 320];   // [w][m][g][col*20 + row] = 80 KB
    __shared__ float pt[VOCABN * 4 * 16];    // [v][g][jj] = 2.5 KB

    const int tid  = threadIdx.x;
    const int w    = tid >> 6;
    const int lane = tid & 63;
    const int l16  = lane & 15;
    const int quad = lane >> 4;
    const int bt   = blockIdx.x & 3;
    const int ht   = blockIdx.x >> 2;
    const int j0   = ht << 4;
    const int b0   = bt << 6;

    // Stage this WG's ptab slice: pt[v][g][jj]
    for (int i = tid; i < VOCABN * 4 * 16; i += 256) {
        int v = i >> 6, r = i & 63, g = r >> 4, jj = r & 15;
        pt[i] = ptab[v * 4096 + g * 1024 + j0 + jj];
    }

    // Load stationary B fragments (once).
    const short* Bbase = (const short*)whb + (((size_t)(j0 + l16)) << 10) + (w << 8) + (quad << 3);
    short8 Bf[4][8];
    #pragma unroll
    for (int g = 0; g < 4; ++g)
        #pragma unroll
        for (int kc = 0; kc < 8; ++kc)
            Bf[g][kc] = *(const short8*)(Bbase + g * (1 << 20) + kc * 32);

    float cst[4] = {0.f, 0.f, 0.f, 0.f};     // c for (batch quad*4+r of M-tile w, hidden j0+l16)

    __syncthreads();                          // pt ready

    const __hip_bfloat16* hin = h0buf;
    __hip_bfloat16* hout = h1buf;
    unsigned* cnt = bar + bt * 64;
    const int brow = (w << 4) + (quad << 2);  // local batch row base (post-reduction ownership)

    for (int t = 0; t < T_SEQ; ++t) {
        // ---- partial GEMM over this wave's K-slice: 4 M-tiles x 4 gates
        const short* Abase = (const short*)hin + (((size_t)(b0 + l16)) << 10) + (w << 8) + (quad << 3);
        floatx4 acc[4][4];
        #pragma unroll
        for (int m = 0; m < 4; ++m) {
            short8 Af[8];
            #pragma unroll
            for (int kc = 0; kc < 8; ++kc)
                Af[kc] = *(const short8*)(Abase + ((m * 16) << 10) + kc * 32);
            #pragma unroll
            for (int g = 0; g < 4; ++g) {
                floatx4 a = {0.f, 0.f, 0.f, 0.f};
                #pragma unroll
                for (int kc = 0; kc < 8; ++kc)
                    a = __builtin_amdgcn_mfma_f32_16x16x32_bf16(Af[kc], Bf[g][kc], a, 0, 0, 0);
                acc[m][g] = a;
            }
        }

        // ---- write partials to LDS (col-major, stride 20 -> <=2-way bank alias)
        #pragma unroll
        for (int m = 0; m < 4; ++m)
            #pragma unroll
            for (int g = 0; g < 4; ++g)
                *(floatx4*)&red[(((w * 4 + m) * 4 + g) * 320) + l16 * 20 + quad * 4] = acc[m][g];
        __syncthreads();

        // ---- K-reduction: wave w owns M-tile w
        floatx4 z[4];
        #pragma unroll
        for (int g = 0; g < 4; ++g) {
            floatx4 s = *(floatx4*)&red[(((0 * 4 + w) * 4 + g) * 320) + l16 * 20 + quad * 4];
            #pragma unroll
            for (int wp = 1; wp < 4; ++wp)
                s += *(floatx4*)&red[(((wp * 4 + w) * 4 + g) * 320) + l16 * 20 + quad * 4];
            z[g] = s;
        }

        // ---- xproj init + gates + register-resident c update + h write
        #pragma unroll
        for (int r = 0; r < 4; ++r) {
            int xv = x[(b0 + brow + r) * T_SEQ + t];
            float zg = z[0][r] + pt[(xv * 4 + 0) * 16 + l16];
            float zi = z[1][r] + pt[(xv * 4 + 1) * 16 + l16];
            float zf = z[2][r] + pt[(xv * 4 + 2) * 16 + l16];
            float zo = z[3][r] + pt[(xv * 4 + 3) * 16 + l16];
            float gv = ftanh(zg), iv = fsig(zi), fv = fsig(zf), ov = fsig(zo);
            float cn = gv * iv + cst[r] * fv;
            cst[r] = cn;
            hout[(((size_t)(b0 + brow + r)) << 10) + j0 + l16] = __float2bfloat16(ftanh(cn) * ov);
        }

        // ---- group barrier (64 WGs sharing this batch-tile), skip after last step
        if (t != T_SEQ - 1) {
            __syncthreads();                  // also fences red[] reuse
            __threadfence();                  // agent-scope release (cross-XCD writeback)
            if (tid == 0) {
                __hip_atomic_fetch_add(cnt, 1u, __ATOMIC_RELEASE, __HIP_MEMORY_SCOPE_AGENT);
                unsigned target = 64u * (unsigned)(t + 1);
                while (__hip_atomic_load(cnt, __ATOMIC_RELAXED, __HIP_MEMORY_SCOPE_AGENT) < target)
                    __builtin_amdgcn_s_sleep(2);
            }
            __syncthreads();
            __threadfence();                  // agent-scope acquire (invalidate stale L1/L2)
        }

        const __hip_bfloat16* tmp = hin; hin = hout; hout = (__hip_bfloat16*)tmp;
    }
}

// y = h @ W_ph^T + b_p : one wave per batch row.
__global__ __launch_bounds__(256)
void final_kernel(const __hip_bfloat16* __restrict__ h, const float* __restrict__ Wph,
                  const float* __restrict__ bp, float* __restrict__ y)
{
    int w = threadIdx.x >> 6;
    int lane = threadIdx.x & 63;
    int b = blockIdx.x * 4 + w;
    float acc[NCLS];
    #pragma unroll
    for (int k = 0; k < NCLS; ++k) acc[k] = 0.0f;
    for (int k = lane; k < HID; k += 64) {
        float hv = __bfloat162float(h[b * HID + k]);
        #pragma unroll
        for (int cls = 0; cls < NCLS; ++cls) acc[cls] += hv * Wph[cls * HID + k];
    }
    #pragma unroll
    for (int cls = 0; cls < NCLS; ++cls) {
        float v = acc[cls];
        #pragma unroll
        for (int off = 32; off > 0; off >>= 1) v += __shfl_down(v, off);
        if (lane == 0) y[b * NCLS + cls] = v + bp[cls];
    }
}

extern "C" void kernel_launch(void* const* d_in, const int* in_sizes, int n_in,
                              void* d_out, int out_size, void* d_ws, size_t ws_size,
                              hipStream_t stream)
{
    const int*   x     = (const int*)d_in[0];
    const float* embed = (const float*)d_in[1];
    const float* Wgx   = (const float*)d_in[2];
    const float* Wix   = (const float*)d_in[3];
    const float* Wfx   = (const float*)d_in[4];
    const float* Wox   = (const float*)d_in[5];
    const float* Wgh   = (const float*)d_in[6];
    const float* Wih   = (const float*)d_in[7];
    const float* Wfh   = (const float*)d_in[8];
    const float* Woh   = (const float*)d_in[9];
    const float* Wph   = (const float*)d_in[10];
    const float* bg    = (const float*)d_in[11];
    const float* bi    = (const float*)d_in[12];
    const float* bf    = (const float*)d_in[13];
    const float* bo    = (const float*)d_in[14];
    const float* bp    = (const float*)d_in[15];
    float* out = (float*)d_out;

    char* ws = (char*)d_ws;
    __hip_bfloat16* whb  = (__hip_bfloat16*)(ws + OFF_WHB);
    float*          ptab = (float*)(ws + OFF_PTAB);
    __hip_bfloat16* h0   = (__hip_bfloat16*)(ws + OFF_H0);
    __hip_bfloat16* h1   = (__hip_bfloat16*)(ws + OFF_H1);
    unsigned*       bar  = (unsigned*)(ws + OFF_BAR);

    prep_kernel<<<16384, 256, 0, stream>>>(Wgh, Wih, Wfh, Woh, embed,
                                           Wgx, Wix, Wfx, Wox,
                                           bg, bi, bf, bo,
                                           whb, ptab, h0, bar);

    lstm_persist<<<256, 256, 0, stream>>>(x, ptab, whb, h0, h1, bar);

    // T=256 even -> final h lives in h0.
    final_kernel<<<64, 256, 0, stream>>>(h0, Wph, bp, out);
}

// Round 3
// 2630.970 us; speedup vs baseline: 4.1631x; 4.1631x over previous
//
#include <hip/hip_runtime.h>
#include <hip/hip_bf16.h>

#define T_SEQ 256
#define BATCH 256
#define HID   1024
#define EMB   10
#define VOCABN 10
#define NCLS  10

typedef __attribute__((ext_vector_type(8))) short short8;
typedef __attribute__((ext_vector_type(4))) float floatx4;

// ---- workspace layout (bytes) ----
#define OFF_WHB   0                                // 4096*1024 bf16 = 8 MB
#define OFF_PTAB  (8*1024*1024)                    // 10*4096 f32 = 160 KB
#define OFF_H0    (OFF_PTAB + 160*1024)            // 256*1024 bf16 = 512 KB
#define OFF_H1    (OFF_H0 + BATCH*HID*2)
#define OFF_BAR   (OFF_H1 + BATCH*HID*2)           // 4 groups x 9 counters x 128B

__device__ __forceinline__ float fsig(float x) {
    return __builtin_amdgcn_rcpf(1.0f + __expf(-x));
}
__device__ __forceinline__ float ftanh(float x) {
    return 2.0f * fsig(2.0f * x) - 1.0f;
}

// One-shot prep: cast Wh -> bf16 gate-major; build ptab; zero h0 + barrier counters.
__global__ __launch_bounds__(256)
void prep_kernel(const float* __restrict__ Wgh, const float* __restrict__ Wih,
                 const float* __restrict__ Wfh, const float* __restrict__ Woh,
                 const float* __restrict__ embed,
                 const float* __restrict__ Wgx, const float* __restrict__ Wix,
                 const float* __restrict__ Wfx, const float* __restrict__ Wox,
                 const float* __restrict__ bg, const float* __restrict__ bi,
                 const float* __restrict__ bf, const float* __restrict__ bo,
                 __hip_bfloat16* __restrict__ whb, float* __restrict__ ptab,
                 __hip_bfloat16* __restrict__ h0, unsigned* __restrict__ bar)
{
    int idx = blockIdx.x * 256 + threadIdx.x;   // 0 .. 4194303
    {
        int gate = idx >> 20;
        int rem  = idx & 0xFFFFF;
        const float* W = (gate == 0) ? Wgh : (gate == 1) ? Wih : (gate == 2) ? Wfh : Woh;
        whb[idx] = __float2bfloat16(W[rem]);
    }
    if (idx < VOCABN * 4 * HID) {               // ptab[v*4096 + g]
        int v = idx >> 12;
        int g = idx & 4095;
        int gg = g >> 10;
        int j  = g & 1023;
        const float* Wx = (gg == 0) ? Wgx : (gg == 1) ? Wix : (gg == 2) ? Wfx : Wox;
        const float* bb = (gg == 0) ? bg  : (gg == 1) ? bi  : (gg == 2) ? bf  : bo;
        float s = bb[j];
        #pragma unroll
        for (int e = 0; e < EMB; ++e) s += embed[v * EMB + e] * Wx[j * EMB + e];
        ptab[idx] = s;
    }
    if (idx < BATCH * HID) h0[idx] = __float2bfloat16(0.0f);
    if (idx < 4 * 9 * 32) bar[idx] = 0u;
}

// Persistent LSTM, weights stationary in registers for all 256 timesteps.
// Grid 256 WGs x 256 thr (84.5KB LDS -> exactly 1 WG/CU -> co-residency guaranteed).
// WG (bt=blk&3, ht=blk>>2): 64 batches x 16 hidden (x4 gates). Wave w: K-slice
// [256w,256w+256), B-frags in 128 VGPRs. K-reduction via LDS; c in registers.
// h exchange: agent-scope relaxed atomics (sc1 -> coherent point, NO L2 inv/wb).
// Inter-step sync: per-group tree barrier (8 leaves + root), monotonic counters.
__global__ __launch_bounds__(256, 1)
void lstm_persist(const int* __restrict__ x, const float* __restrict__ ptab,
                  const __hip_bfloat16* __restrict__ whb,
                  __hip_bfloat16* __restrict__ h0buf,
                  __hip_bfloat16* __restrict__ h1buf,
                  unsigned* __restrict__ bar)
{
    __shared__ float red[4 * 4 * 4 * 320];   // [w][m][g][col*20 + row] = 80 KB
    __shared__ float pt[VOCABN * 64];        // [v][g][jj] = 2.5 KB

    const int tid  = threadIdx.x;
    const int w    = tid >> 6;
    const int lane = tid & 63;
    const int l16  = lane & 15;
    const int quad = lane >> 4;
    const int bt   = blockIdx.x & 3;
    const int j0   = (blockIdx.x >> 2) << 4;
    const int b0   = bt << 6;
    // leaf mates differ by blk+=32 -> same XCD under round-robin (heuristic only)
    const int leaf = (blockIdx.x >> 2) & 7;
    unsigned* leafc = bar + (bt * 9 + leaf) * 32;
    unsigned* rootc = bar + (bt * 9 + 8) * 32;

    for (int i = tid; i < VOCABN * 64; i += 256) {
        int v = i >> 6, r = i & 63, g = r >> 4, jj = r & 15;
        pt[i] = ptab[v * 4096 + g * 1024 + j0 + jj];
    }

    // Stationary B fragments (loaded once, normal cached loads).
    const short* Bbase = (const short*)whb + (((size_t)(j0 + l16)) << 10) + (w << 8) + (quad << 3);
    short8 Bf[4][8];
    #pragma unroll
    for (int g = 0; g < 4; ++g)
        #pragma unroll
        for (int kc = 0; kc < 8; ++kc)
            Bf[g][kc] = *(const short8*)(Bbase + g * (1 << 20) + kc * 32);

    float cst[4] = {0.f, 0.f, 0.f, 0.f};
    __syncthreads();                          // pt ready

    unsigned long long hinA  = (unsigned long long)h0buf;
    unsigned long long houtA = (unsigned long long)h1buf;
    const int brow = (w << 4) + (quad << 2);  // post-reduction batch-row ownership

    for (int t = 0; t < T_SEQ; ++t) {
        // Early x fetch (L1/L2-hot, hides latency past the GEMM).
        int xv[4];
        #pragma unroll
        for (int r = 0; r < 4; ++r) xv[r] = x[(b0 + brow + r) * T_SEQ + t];

        // ---- partial GEMM over this wave's K-slice (h via coherent 8B loads)
        const unsigned long long* Au = (const unsigned long long*)hinA
            + (((size_t)(b0 + l16)) << 8) + (w << 6) + (quad << 1);
        floatx4 acc[4][4];
        #pragma unroll
        for (int m = 0; m < 4; ++m) {
            union { unsigned long long u[2]; short8 s; } Af[8];
            const unsigned long long* Ab = Au + (m << 12);
            #pragma unroll
            for (int kc = 0; kc < 8; ++kc) {
                Af[kc].u[0] = __hip_atomic_load(Ab + kc * 8,     __ATOMIC_RELAXED, __HIP_MEMORY_SCOPE_AGENT);
                Af[kc].u[1] = __hip_atomic_load(Ab + kc * 8 + 1, __ATOMIC_RELAXED, __HIP_MEMORY_SCOPE_AGENT);
            }
            #pragma unroll
            for (int g = 0; g < 4; ++g) {
                floatx4 a = {0.f, 0.f, 0.f, 0.f};
                #pragma unroll
                for (int kc = 0; kc < 8; ++kc)
                    a = __builtin_amdgcn_mfma_f32_16x16x32_bf16(Af[kc].s, Bf[g][kc], a, 0, 0, 0);
                acc[m][g] = a;
            }
        }

        // ---- K-reduction through LDS; wave w owns M-tile w
        #pragma unroll
        for (int m = 0; m < 4; ++m)
            #pragma unroll
            for (int g = 0; g < 4; ++g)
                *(floatx4*)&red[(((w * 4 + m) * 4 + g) * 320) + l16 * 20 + quad * 4] = acc[m][g];
        __syncthreads();

        floatx4 z[4];
        #pragma unroll
        for (int g = 0; g < 4; ++g) {
            floatx4 s = *(floatx4*)&red[((w * 4 + g) * 320) + l16 * 20 + quad * 4];
            #pragma unroll
            for (int wp = 1; wp < 4; ++wp)
                s += *(floatx4*)&red[(((wp * 4 + w) * 4 + g) * 320) + l16 * 20 + quad * 4];
            z[g] = s;
        }

        // ---- gates + register-resident c + coherent h write
        unsigned short* ho = (unsigned short*)houtA;
        #pragma unroll
        for (int r = 0; r < 4; ++r) {
            int pb = (xv[r] << 6) + l16;
            float zg = z[0][r] + pt[pb];
            float zi = z[1][r] + pt[pb + 16];
            float zf = z[2][r] + pt[pb + 32];
            float zo = z[3][r] + pt[pb + 48];
            float gv = ftanh(zg), iv = fsig(zi), fv = fsig(zf), ov = fsig(zo);
            float cn = gv * iv + cst[r] * fv;
            cst[r] = cn;
            __hip_bfloat16 hb = __float2bfloat16(ftanh(cn) * ov);
            __hip_atomic_store(ho + (((size_t)(b0 + brow + r)) << 10) + j0 + l16,
                               __builtin_bit_cast(unsigned short, hb),
                               __ATOMIC_RELAXED, __HIP_MEMORY_SCOPE_AGENT);
        }

        // ---- tree barrier over the 64 WGs of this batch group
        if (t != T_SEQ - 1) {
            __syncthreads();   // drains vmcnt(0): h stores at coherent point; red reusable
            if (tid == 0) {
                unsigned tgt = 8u * (unsigned)(t + 1);
                unsigned old = __hip_atomic_fetch_add(leafc, 1u, __ATOMIC_RELAXED,
                                                      __HIP_MEMORY_SCOPE_AGENT);
                if (old == tgt - 1u)
                    __hip_atomic_fetch_add(rootc, 1u, __ATOMIC_RELAXED,
                                           __HIP_MEMORY_SCOPE_AGENT);
                while (__hip_atomic_load(rootc, __ATOMIC_RELAXED,
                                         __HIP_MEMORY_SCOPE_AGENT) < tgt)
                    __builtin_amdgcn_s_sleep(2);
            }
            __syncthreads();
        }

        unsigned long long tmp = hinA; hinA = houtA; houtA = tmp;
    }
}

// y = h @ W_ph^T + b_p : one wave per batch row.
__global__ __launch_bounds__(256)
void final_kernel(const __hip_bfloat16* __restrict__ h, const float* __restrict__ Wph,
                  const float* __restrict__ bp, float* __restrict__ y)
{
    int w = threadIdx.x >> 6;
    int lane = threadIdx.x & 63;
    int b = blockIdx.x * 4 + w;
    float acc[NCLS];
    #pragma unroll
    for (int k = 0; k < NCLS; ++k) acc[k] = 0.0f;
    for (int k = lane; k < HID; k += 64) {
        float hv = __bfloat162float(h[b * HID + k]);
        #pragma unroll
        for (int cls = 0; cls < NCLS; ++cls) acc[cls] += hv * Wph[cls * HID + k];
    }
    #pragma unroll
    for (int cls = 0; cls < NCLS; ++cls) {
        float v = acc[cls];
        #pragma unroll
        for (int off = 32; off > 0; off >>= 1) v += __shfl_down(v, off);
        if (lane == 0) y[b * NCLS + cls] = v + bp[cls];
    }
}

extern "C" void kernel_launch(void* const* d_in, const int* in_sizes, int n_in,
                              void* d_out, int out_size, void* d_ws, size_t ws_size,
                              hipStream_t stream)
{
    const int*   x     = (const int*)d_in[0];
    const float* embed = (const float*)d_in[1];
    const float* Wgx   = (const float*)d_in[2];
    const float* Wix   = (const float*)d_in[3];
    const float* Wfx   = (const float*)d_in[4];
    const float* Wox   = (const float*)d_in[5];
    const float* Wgh   = (const float*)d_in[6];
    const float* Wih   = (const float*)d_in[7];
    const float* Wfh   = (const float*)d_in[8];
    const float* Woh   = (const float*)d_in[9];
    const float* Wph   = (const float*)d_in[10];
    const float* bg    = (const float*)d_in[11];
    const float* bi    = (const float*)d_in[12];
    const float* bf    = (const float*)d_in[13];
    const float* bo    = (const float*)d_in[14];
    const float* bp    = (const float*)d_in[15];
    float* out = (float*)d_out;

    char* ws = (char*)d_ws;
    __hip_bfloat16* whb  = (__hip_bfloat16*)(ws + OFF_WHB);
    float*          ptab = (float*)(ws + OFF_PTAB);
    __hip_bfloat16* h0   = (__hip_bfloat16*)(ws + OFF_H0);
    __hip_bfloat16* h1   = (__hip_bfloat16*)(ws + OFF_H1);
    unsigned*       bar  = (unsigned*)(ws + OFF_BAR);

    prep_kernel<<<16384, 256, 0, stream>>>(Wgh, Wih, Wfh, Woh, embed,
                                           Wgx, Wix, Wfx, Wox,
                                           bg, bi, bf, bo,
                                           whb, ptab, h0, bar);

    lstm_persist<<<256, 256, 0, stream>>>(x, ptab, whb, h0, h1, bar);

    // T=256 even -> final h lives in h0.
    final_kernel<<<64, 256, 0, stream>>>(h0, Wph, bp, out);
}

// Round 4
// 1972.943 us; speedup vs baseline: 5.5516x; 1.3335x over previous
//
#include <hip/hip_runtime.h>
#include <hip/hip_bf16.h>

#define T_SEQ 256
#define BATCH 256
#define HID   1024
#define EMB   10
#define VOCABN 10
#define NCLS  10

typedef __attribute__((ext_vector_type(8))) short short8;
typedef __attribute__((ext_vector_type(4))) float floatx4;
typedef unsigned long long ull;

// ---- workspace layout (bytes) ----
#define OFF_WHB   0                                // 4096*1024 bf16 = 8 MB
#define OFF_PTAB  (8*1024*1024)                    // 10*4096 f32 = 160 KB
#define OFF_H0    (OFF_PTAB + 160*1024)            // 256*1024 bf16 = 512 KB
#define OFF_H1    (OFF_H0 + BATCH*HID*2)
#define OFF_BAR   (OFF_H1 + BATCH*HID*2)           // 8 groups x 4 quarters x 128B

__device__ __forceinline__ float fsig(float x) {
    return __builtin_amdgcn_rcpf(1.0f + __expf(-x));
}
__device__ __forceinline__ float ftanh(float x) {
    return 2.0f * fsig(2.0f * x) - 1.0f;
}

// One-shot prep: cast Wh -> bf16 gate-major; build ptab; zero h0 + counters.
__global__ __launch_bounds__(256)
void prep_kernel(const float* __restrict__ Wgh, const float* __restrict__ Wih,
                 const float* __restrict__ Wfh, const float* __restrict__ Woh,
                 const float* __restrict__ embed,
                 const float* __restrict__ Wgx, const float* __restrict__ Wix,
                 const float* __restrict__ Wfx, const float* __restrict__ Wox,
                 const float* __restrict__ bg, const float* __restrict__ bi,
                 const float* __restrict__ bf, const float* __restrict__ bo,
                 __hip_bfloat16* __restrict__ whb, float* __restrict__ ptab,
                 __hip_bfloat16* __restrict__ h0, unsigned* __restrict__ bar)
{
    int idx = blockIdx.x * 256 + threadIdx.x;   // 0 .. 4194303
    {
        int gate = idx >> 20;
        int rem  = idx & 0xFFFFF;
        const float* W = (gate == 0) ? Wgh : (gate == 1) ? Wih : (gate == 2) ? Wfh : Woh;
        whb[idx] = __float2bfloat16(W[rem]);
    }
    if (idx < VOCABN * 4 * HID) {               // ptab[v*4096 + g]
        int v = idx >> 12;
        int g = idx & 4095;
        int gg = g >> 10;
        int j  = g & 1023;
        const float* Wx = (gg == 0) ? Wgx : (gg == 1) ? Wix : (gg == 2) ? Wfx : Wox;
        const float* bb = (gg == 0) ? bg  : (gg == 1) ? bi  : (gg == 2) ? bf  : bo;
        float s = bb[j];
        #pragma unroll
        for (int e = 0; e < EMB; ++e) s += embed[v * EMB + e] * Wx[j * EMB + e];
        ptab[idx] = s;
    }
    if (idx < BATCH * HID) h0[idx] = __float2bfloat16(0.0f);
    if (idx < 8 * 4 * 32) bar[idx] = 0u;
}

// Persistent LSTM, weights stationary in registers for all 256 timesteps.
// Grid 256 WGs x 256 thr (~85KB LDS -> exactly 1 WG/CU -> co-residency).
// WG (bt=blk&7, ht=blk>>3): 32 batches x 32 hidden (x4 gates). Wave w: K-slice
// [256w,256w+256); B-frags 8 n x 8 kc = 256 VGPRs, loaded once.
// h exchange: agent-scope relaxed atomics (bypass non-coherent per-XCD L2).
// Inter-step sync: per-(group,K-quarter) producer counters; wave w spins only
// on quarter w (8 producers) right before its A-loads. WAR on the h ping-pong
// buffers is transitively ordered by each WG's internal reduction barrier.
__global__ __launch_bounds__(256, 1)
void lstm_persist(const int* __restrict__ x, const float* __restrict__ ptab,
                  const __hip_bfloat16* __restrict__ whb,
                  __hip_bfloat16* __restrict__ h0buf,
                  __hip_bfloat16* __restrict__ h1buf,
                  unsigned* __restrict__ bar)
{
    __shared__ float red[4 * 2 * 8 * 320];   // [wave][m][n][col*20+row] = 80 KB
    __shared__ float pt[VOCABN * 128];       // [v][g][jj2] = 5 KB

    const int tid  = threadIdx.x;
    const int w    = tid >> 6;
    const int lane = tid & 63;
    const int l16  = lane & 15;
    const int quad = lane >> 4;
    const int bt   = blockIdx.x & 7;          // batch group (same XCD under %8 map)
    const int ht   = blockIdx.x >> 3;         // 0..31 hidden tile
    const int j0   = ht << 5;
    const int b0   = bt << 5;
    const int mw   = w >> 1;                  // owned m-tile (post-reduction)
    const int jb   = w & 1;                   // owned 16-col half of the 32-hid tile

    unsigned* myq  = bar + ((bt << 2) + w) * 32;          // quarter this wave consumes
    unsigned* sigq = bar + ((bt << 2) + (ht >> 3)) * 32;  // quarter this WG produces

    // Stage ptab slice: pt[v*128 + g*32 + jj2]
    for (int i = tid; i < VOCABN * 128; i += 256) {
        int v = i >> 7, r = i & 127, g = r >> 5, jj2 = r & 31;
        pt[i] = ptab[v * 4096 + g * 1024 + j0 + jj2];
    }

    // Stationary B fragments: n-frag n -> gate n>>1, col-half (n&1)*16.
    short8 Bf[8][8];
    #pragma unroll
    for (int n = 0; n < 8; ++n) {
        const short* p = (const short*)whb + (((size_t)(n >> 1)) << 20)
                       + (((size_t)(j0 + ((n & 1) << 4) + l16)) << 10)
                       + (w << 8) + (quad << 3);
        #pragma unroll
        for (int kc = 0; kc < 8; ++kc)
            Bf[n][kc] = *(const short8*)(p + kc * 32);
    }

    float cst[4] = {0.f, 0.f, 0.f, 0.f};
    __syncthreads();                          // pt ready

    ull hinA  = (ull)h0buf;
    ull houtA = (ull)h1buf;
    const int brow = (mw << 4) + (quad << 2); // owned batch-row base (local)

    #pragma unroll 1
    for (int t = 0; t < T_SEQ; ++t) {
        // x fetch first (independent of h readiness).
        int xv[4];
        #pragma unroll
        for (int r = 0; r < 4; ++r) xv[r] = x[(b0 + brow + r) * T_SEQ + t];

        // ---- per-wave spin: wait for the 8 producers of K-quarter w.
        if (t) {
            unsigned tgt = (unsigned)(t << 3);
            if (lane == 0) {
                while (__hip_atomic_load(myq, __ATOMIC_RELAXED, __HIP_MEMORY_SCOPE_AGENT) < tgt)
                    __builtin_amdgcn_s_sleep(4);
            }
        }

        // ---- partial GEMM over this wave's K-slice: 2 m-tiles x 8 n-frags.
        const ull* Au = (const ull*)hinA + (((size_t)(b0 + l16)) << 8) + (w << 6) + (quad << 1);
        floatx4 acc[2][8];
        #pragma unroll
        for (int m = 0; m < 2; ++m) {
            union { ull u[2]; short8 s; } Af[8];
            const ull* Ab = Au + (m << 12);
            #pragma unroll
            for (int kc = 0; kc < 8; ++kc) {
                Af[kc].u[0] = __hip_atomic_load(Ab + kc * 8,     __ATOMIC_RELAXED, __HIP_MEMORY_SCOPE_AGENT);
                Af[kc].u[1] = __hip_atomic_load(Ab + kc * 8 + 1, __ATOMIC_RELAXED, __HIP_MEMORY_SCOPE_AGENT);
            }
            #pragma unroll
            for (int n = 0; n < 8; ++n) {
                floatx4 a = {0.f, 0.f, 0.f, 0.f};
                #pragma unroll
                for (int kc = 0; kc < 8; ++kc)
                    a = __builtin_amdgcn_mfma_f32_16x16x32_bf16(Af[kc].s, Bf[n][kc], a, 0, 0, 0);
                acc[m][n] = a;
            }
        }

        // ---- K-reduction through LDS; wave w owns (m=mw, col-half jb).
        #pragma unroll
        for (int m = 0; m < 2; ++m)
            #pragma unroll
            for (int n = 0; n < 8; ++n)
                *(floatx4*)&red[(((w * 2 + m) * 8 + n) * 320) + l16 * 20 + quad * 4] = acc[m][n];
        __syncthreads();

        floatx4 z[4];
        #pragma unroll
        for (int g = 0; g < 4; ++g) {
            int n = (g << 1) + jb;
            floatx4 s = *(floatx4*)&red[((mw * 8 + n) * 320) + l16 * 20 + quad * 4];
            #pragma unroll
            for (int wp = 1; wp < 4; ++wp)
                s += *(floatx4*)&red[(((wp * 2 + mw) * 8 + n) * 320) + l16 * 20 + quad * 4];
            z[g] = s;
        }

        // ---- gates + register-resident c + coherent h write.
        unsigned short* ho = (unsigned short*)houtA;
        const int jcol = j0 + (jb << 4) + l16;
        #pragma unroll
        for (int r = 0; r < 4; ++r) {
            int pb = (xv[r] << 7) + (jb << 4) + l16;
            float zg = z[0][r] + pt[pb];
            float zi = z[1][r] + pt[pb + 32];
            float zf = z[2][r] + pt[pb + 64];
            float zo = z[3][r] + pt[pb + 96];
            float gv = ftanh(zg), iv = fsig(zi), fv = fsig(zf), ov = fsig(zo);
            float cn = gv * iv + cst[r] * fv;
            cst[r] = cn;
            __hip_bfloat16 hb = __float2bfloat16(ftanh(cn) * ov);
            __hip_atomic_store(ho + (((size_t)(b0 + brow + r)) << 10) + jcol,
                               __builtin_bit_cast(unsigned short, hb),
                               __ATOMIC_RELAXED, __HIP_MEMORY_SCOPE_AGENT);
        }

        // ---- signal: all 4 waves' h-stores drained (syncthreads waits vmcnt(0)
        // per wave before the barrier), then one add to this WG's quarter counter.
        if (t != T_SEQ - 1) {
            __syncthreads();
            if (tid == 0)
                __hip_atomic_fetch_add(sigq, 1u, __ATOMIC_RELAXED, __HIP_MEMORY_SCOPE_AGENT);
        }

        ull tmp = hinA; hinA = houtA; houtA = tmp;
    }
}

// y = h @ W_ph^T + b_p : one wave per batch row.
__global__ __launch_bounds__(256)
void final_kernel(const __hip_bfloat16* __restrict__ h, const float* __restrict__ Wph,
                  const float* __restrict__ bp, float* __restrict__ y)
{
    int w = threadIdx.x >> 6;
    int lane = threadIdx.x & 63;
    int b = blockIdx.x * 4 + w;
    float acc[NCLS];
    #pragma unroll
    for (int k = 0; k < NCLS; ++k) acc[k] = 0.0f;
    for (int k = lane; k < HID; k += 64) {
        float hv = __bfloat162float(h[b * HID + k]);
        #pragma unroll
        for (int cls = 0; cls < NCLS; ++cls) acc[cls] += hv * Wph[cls * HID + k];
    }
    #pragma unroll
    for (int cls = 0; cls < NCLS; ++cls) {
        float v = acc[cls];
        #pragma unroll
        for (int off = 32; off > 0; off >>= 1) v += __shfl_down(v, off);
        if (lane == 0) y[b * NCLS + cls] = v + bp[cls];
    }
}

extern "C" void kernel_launch(void* const* d_in, const int* in_sizes, int n_in,
                              void* d_out, int out_size, void* d_ws, size_t ws_size,
                              hipStream_t stream)
{
    const int*   x     = (const int*)d_in[0];
    const float* embed = (const float*)d_in[1];
    const float* Wgx   = (const float*)d_in[2];
    const float* Wix   = (const float*)d_in[3];
    const float* Wfx   = (const float*)d_in[4];
    const float* Wox   = (const float*)d_in[5];
    const float* Wgh   = (const float*)d_in[6];
    const float* Wih   = (const float*)d_in[7];
    const float* Wfh   = (const float*)d_in[8];
    const float* Woh   = (const float*)d_in[9];
    const float* Wph   = (const float*)d_in[10];
    const float* bg    = (const float*)d_in[11];
    const float* bi    = (const float*)d_in[12];
    const float* bf    = (const float*)d_in[13];
    const float* bo    = (const float*)d_in[14];
    const float* bp    = (const float*)d_in[15];
    float* out = (float*)d_out;

    char* ws = (char*)d_ws;
    __hip_bfloat16* whb  = (__hip_bfloat16*)(ws + OFF_WHB);
    float*          ptab = (float*)(ws + OFF_PTAB);
    __hip_bfloat16* h0   = (__hip_bfloat16*)(ws + OFF_H0);
    __hip_bfloat16* h1   = (__hip_bfloat16*)(ws + OFF_H1);
    unsigned*       bar  = (unsigned*)(ws + OFF_BAR);

    prep_kernel<<<16384, 256, 0, stream>>>(Wgh, Wih, Wfh, Woh, embed,
                                           Wgx, Wix, Wfx, Wox,
                                           bg, bi, bf, bo,
                                           whb, ptab, h0, bar);

    lstm_persist<<<256, 256, 0, stream>>>(x, ptab, whb, h0, h1, bar);

    // T=256 even -> final h lives in h0.
    final_kernel<<<64, 256, 0, stream>>>(h0, Wph, bp, out);
}